// Round 7
// baseline (64.889 us; speedup 1.0000x reference)
//
#include <hip/hip_runtime.h>

// Problem constants (fixed shapes from setup_inputs)
constexpr int NB = 8;     // batch
constexpr int ND = 1024;  // d = 32*32 cells
constexpr int NS = 500;   // noise samples n
constexpr int NK = 16;    // k
constexpr int NC = 3;     // channels
constexpr int NH = 1024;  // H
constexpr int NW = 1024;  // W
constexpr int NP = 64;    // patch size
constexpr int PTOP = 16;  // (p - sh)/2
constexpr int PLEFT = 16; // (p - sw)/2
constexpr float SIGMA = 0.05f;

// ---- Phase 1: normalize (blocks 0-7) + zero counts (all 64 blocks) ----
__global__ void normalize_kernel(const float* __restrict__ scores,
                                 float* __restrict__ s_norm,
                                 int* __restrict__ counts) {
    int blk = blockIdx.x;   // 64 blocks
    int t = threadIdx.x;

    // zero counts: 8*16*1024 ints = 32768 int4; 512 int4 per block
    int4 z4 = make_int4(0, 0, 0, 0);
    ((int4*)counts)[blk * 512 + t] = z4;
    ((int4*)counts)[blk * 512 + 256 + t] = z4;

    if (blk >= NB) return;
    int b = blk;
    float v[4];
#pragma unroll
    for (int q = 0; q < 4; q++) v[q] = scores[b * ND + t + 256 * q];
    float mn = fminf(fminf(v[0], v[1]), fminf(v[2], v[3]));
    float mx = fmaxf(fmaxf(v[0], v[1]), fmaxf(v[2], v[3]));
#pragma unroll
    for (int off = 1; off < 64; off <<= 1) {
        mn = fminf(mn, __shfl_xor(mn, off));
        mx = fmaxf(mx, __shfl_xor(mx, off));
    }
    __shared__ float smn[4], smx[4];
    int wave = t >> 6, lane = t & 63;
    if (lane == 0) { smn[wave] = mn; smx[wave] = mx; }
    __syncthreads();
    mn = fminf(fminf(smn[0], smn[1]), fminf(smn[2], smn[3]));
    mx = fmaxf(fmaxf(smx[0], smx[1]), fmaxf(smx[2], smx[3]));
    float den = mx - mn + 1e-5f;
#pragma unroll
    for (int q = 0; q < 4; q++)
        s_norm[b * ND + t + 256 * q] = (v[q] - mn) / den;
}

// ---------------- Phase 2: wave-per-sample top-16 -> integer histogram ----------------
__global__ void topk_kernel(const float* __restrict__ s_norm,
                            const float* __restrict__ noise,
                            int* __restrict__ counts) {
    int t = threadIdx.x;
    int wave = t >> 6, lane = t & 63;
    int sid = blockIdx.x * 4 + wave;          // 0 .. NB*NS-1 (grid is exact)
    int b = sid / NS;

    const float* sp = s_norm + b * ND;
    const float* npp = noise + (size_t)sid * ND;

    float v[16];
#pragma unroll
    for (int q = 0; q < 16; q++) {
        int j = q * 64 + lane;
        v[q] = sp[j] + npp[j] * SIGMA;
    }

    int myj = 0x7fffffff;
    for (int it = 0; it < NK; it++) {
        float bv = v[0];
        int bq = 0;
#pragma unroll
        for (int q = 1; q < 16; q++)
            if (v[q] > bv) { bv = v[q]; bq = q; }
        int bj = bq * 64 + lane;
#pragma unroll
        for (int off = 1; off < 64; off <<= 1) {
            float ov = __shfl_xor(bv, off);
            int oj = __shfl_xor(bj, off);
            if (ov > bv || (ov == bv && oj < bj)) { bv = ov; bj = oj; }
        }
        if (lane == it) myj = bj;
        int wq = bj >> 6, wl = bj & 63;
#pragma unroll
        for (int q = 0; q < 16; q++)
            v[q] = (q == wq && lane == wl) ? -1e30f : v[q];
    }

    int rank = 0;
#pragma unroll
    for (int u = 0; u < NK; u++) {
        int other = __shfl(myj, u);
        rank += (other < myj) ? 1 : 0;
    }
    if (lane < NK)
        atomicAdd(&counts[(b * NK + rank) * ND + myj], 1);
}

// ---------------- Phase 2.5: per-batch union of nonzero cells ----------------
// Block per b. Entry = packed (i<<15)|(j<<5)|edge_flags; + 16 f32 weights.
__global__ void union_kernel(const int* __restrict__ counts,
                             int* __restrict__ ucell,
                             float* __restrict__ uw,
                             int* __restrict__ nunion) {
    int b = blockIdx.x;
    int t = threadIdx.x;
    int lane = t & 63, wave = t >> 6;
    const int* cp = counts + b * NK * ND;

    unsigned nz = 0;
    for (int kk = 0; kk < NK; kk++) {
        int4 c4 = *(const int4*)(cp + kk * ND + t * 4);
        if (c4.x) nz |= 1;
        if (c4.y) nz |= 2;
        if (c4.z) nz |= 4;
        if (c4.w) nz |= 8;
    }
    int cnt = __popc(nz);
    int incl = cnt;
#pragma unroll
    for (int off = 1; off < 64; off <<= 1) {
        int o = __shfl_up(incl, off);
        if (lane >= off) incl += o;
    }
    int excl = incl - cnt;
    __shared__ int wtot[4];
    if (lane == 63) wtot[wave] = incl;
    __syncthreads();
    int base = 0;
    for (int w = 0; w < wave; w++) base += wtot[w];
    int pos = base + excl;

    const float invn = 1.0f / (float)NS;
    int* up = ucell + b * ND;
    float* wp = uw + (size_t)b * ND * NK;
#pragma unroll
    for (int q = 0; q < 4; q++) {
        if (nz & (1u << q)) {
            int cell = t * 4 + q;
            int i = cell >> 5, j = cell & 31;
            int ent = (i << 15) | (j << 5) |
                      ((i == 0) ? 1 : 0) | ((i == 31) ? 2 : 0) |
                      ((j == 0) ? 4 : 0) | ((j == 31) ? 8 : 0);
            up[pos] = ent;
            for (int kk = 0; kk < NK; kk++)
                wp[(size_t)pos * NK + kk] = (float)cp[kk * ND + cell] * invn;
            pos++;
        }
    }
    if (t == 0) nunion[b] = wtot[0] + wtot[1] + wtot[2] + wtot[3];
}

// ---------------- Phase 3: union gather, float4 x 4-entry-parallel ----------------
// Grid: blk = ii*24 + bc (bc = b*3+c; blk%8==bc%8 pins each image to one XCD).
// ii = gg(0..15) | kq<<4. Wave w handles output row y = gg*4 + w.
// Lane = (e4<<4)|c4: 16-lane group e4 owns entry base+4j+e4, cols [4c4,4c4+4).
// Patch geometry: every 4-col group is wholly in- or out-of-image (all offsets
// = 0 mod 4), so one float4 load per lane per entry covers 4 output px. One
// wave-load serves 64px x 4 entries -> 16x fewer load instructions than 4B/entry.
// Entry partial sums combined by shfl_xor(16/32) butterfly at the end; e4 group
// writes kk pair {kq*8+2*e4, +1}. Every output written exactly once.
constexpr int MAXE = 768;
__global__ void gather_kernel(const int* __restrict__ ucell,
                              const float* __restrict__ uw,
                              const int* __restrict__ nunion,
                              const float* __restrict__ x_high,
                              float* __restrict__ out) {
    int blk = blockIdx.x;
    int bc = blk % 24;
    int ii = blk / 24;           // 0..31
    int gg = ii & 15;
    int kq = ii >> 4;            // kk half: 0 or 1
    int b = bc / 3, c = bc % 3;
    int t = threadIdx.x;
    int w = t >> 6;              // wave -> output row
    int lane = t & 63;
    int e4 = lane >> 4;          // entry sub-slot 0..3
    int c4 = lane & 15;          // col group: cols [4c4, 4c4+4)
    int y = gg * 4 + w;

    int m = nunion[b];
    int mc = m < MAXE ? m : MAXE;

    __shared__ int lc[MAXE];        // 3 KB
    __shared__ float lw[MAXE][8];   // 24 KB

    for (int i = t; i < mc; i += 256) {
        lc[i] = ucell[b * ND + i];
        const float4* wsrc =
            (const float4*)(uw + (size_t)(b * ND + i) * NK + kq * 8);
        float4 w0 = wsrc[0], w1 = wsrc[1];
        *(float4*)&lw[i][0] = w0;
        *(float4*)&lw[i][4] = w1;
    }
    __syncthreads();

    const float* xp = x_high + (size_t)bc * (NH * NW);
    int ym = y - PTOP;           // [-16, 48)
    int xm = 4 * c4 - PLEFT;     // [-16, 48), multiple of 4
    int off = ym * NW + xm;
    int mask = ((ym < 0) ? 1 : 0) | ((ym >= 32) ? 2 : 0) |
               ((xm < 0) ? 4 : 0) | ((xm >= 32) ? 8 : 0);

    float4 acc4[8];
#pragma unroll
    for (int q = 0; q < 8; q++) acc4[q] = make_float4(0.f, 0.f, 0.f, 0.f);

    for (int base = 0; base < mc; base += 16) {
        float4 vv[4];
        int es[4];
        // phase A: 4 independent float4 loads (4 entries per wave in flight)
#pragma unroll
        for (int j = 0; j < 4; j++) {
            int ee = base + j * 4 + e4;
            bool in = (ee < mc);
            int e = in ? ee : 0;
            es[j] = e;
            int ent = lc[e];
            bool ok = in && ((ent & mask) == 0);
            int idx = ok ? ((ent & ~15) + off) : 0;
            float4 v = *(const float4*)(xp + idx);
            vv[j].x = ok ? v.x : 0.f;
            vv[j].y = ok ? v.y : 0.f;
            vv[j].z = ok ? v.z : 0.f;
            vv[j].w = ok ? v.w : 0.f;
        }
        // phase B: consume (8 kk x 4 cols = 32 FMA per entry-slot)
#pragma unroll
        for (int j = 0; j < 4; j++) {
            float4 w0 = *(const float4*)&lw[es[j]][0];
            float4 w1 = *(const float4*)&lw[es[j]][4];
            float4 v = vv[j];
            acc4[0].x += w0.x * v.x; acc4[0].y += w0.x * v.y; acc4[0].z += w0.x * v.z; acc4[0].w += w0.x * v.w;
            acc4[1].x += w0.y * v.x; acc4[1].y += w0.y * v.y; acc4[1].z += w0.y * v.z; acc4[1].w += w0.y * v.w;
            acc4[2].x += w0.z * v.x; acc4[2].y += w0.z * v.y; acc4[2].z += w0.z * v.z; acc4[2].w += w0.z * v.w;
            acc4[3].x += w0.w * v.x; acc4[3].y += w0.w * v.y; acc4[3].z += w0.w * v.z; acc4[3].w += w0.w * v.w;
            acc4[4].x += w1.x * v.x; acc4[4].y += w1.x * v.y; acc4[4].z += w1.x * v.z; acc4[4].w += w1.x * v.w;
            acc4[5].x += w1.y * v.x; acc4[5].y += w1.y * v.y; acc4[5].z += w1.y * v.z; acc4[5].w += w1.y * v.w;
            acc4[6].x += w1.z * v.x; acc4[6].y += w1.z * v.y; acc4[6].z += w1.z * v.z; acc4[6].w += w1.z * v.w;
            acc4[7].x += w1.w * v.x; acc4[7].y += w1.w * v.y; acc4[7].z += w1.w * v.z; acc4[7].w += w1.w * v.w;
        }
    }

    // overflow tail (m > MAXE) — correctness only, statistically never runs
    for (int e = MAXE; e < m; e++) {
        int ent = ucell[b * ND + e];
        bool ok = ((ent & mask) == 0);
        int idx = ok ? ((ent & ~15) + off) : 0;
        float4 v = *(const float4*)(xp + idx);
        if (!ok) v = make_float4(0.f, 0.f, 0.f, 0.f);
        const float* wq = uw + (size_t)(b * ND + e) * NK + kq * 8;
        if (e4 == 0) {   // only one entry-slot active in tail; others add zero
#pragma unroll
            for (int q = 0; q < 8; q++) {
                float wv = wq[q];
                acc4[q].x += wv * v.x; acc4[q].y += wv * v.y;
                acc4[q].z += wv * v.z; acc4[q].w += wv * v.w;
            }
        }
    }

    // combine the 4 entry-slot partial sums: butterfly over lane bits 4,5
#pragma unroll
    for (int q = 0; q < 8; q++) {
        acc4[q].x += __shfl_xor(acc4[q].x, 16);
        acc4[q].y += __shfl_xor(acc4[q].y, 16);
        acc4[q].z += __shfl_xor(acc4[q].z, 16);
        acc4[q].w += __shfl_xor(acc4[q].w, 16);
        acc4[q].x += __shfl_xor(acc4[q].x, 32);
        acc4[q].y += __shfl_xor(acc4[q].y, 32);
        acc4[q].z += __shfl_xor(acc4[q].z, 32);
        acc4[q].w += __shfl_xor(acc4[q].w, 32);
    }

    // e4 group writes kk pair {2*e4, 2*e4+1} of this half (static index select)
    float4 r0 = (e4 == 0) ? acc4[0] : (e4 == 1) ? acc4[2] : (e4 == 2) ? acc4[4] : acc4[6];
    float4 r1 = (e4 == 0) ? acc4[1] : (e4 == 1) ? acc4[3] : (e4 == 2) ? acc4[5] : acc4[7];
    int kk0 = kq * 8 + e4 * 2;
    size_t o0 = ((size_t)(b * NK + kk0) * NC + c) * (NP * NP) + y * NP + 4 * c4;
    size_t o1 = ((size_t)(b * NK + kk0 + 1) * NC + c) * (NP * NP) + y * NP + 4 * c4;
    *(float4*)(out + o0) = r0;
    *(float4*)(out + o1) = r1;
}

extern "C" void kernel_launch(void* const* d_in, const int* in_sizes, int n_in,
                              void* d_out, int out_size, void* d_ws, size_t ws_size,
                              hipStream_t stream) {
    const float* scores = (const float*)d_in[0];
    const float* x_high = (const float*)d_in[1];
    const float* noise  = (const float*)d_in[2];

    char* ws = (char*)d_ws;
    float* s_norm = (float*)ws;                            // 32 KB
    int* counts   = (int*)(ws + 32 * 1024);                // 512 KB (int4-aligned)
    int* ucell    = (int*)(ws + 544 * 1024);               // 32 KB
    float* uw     = (float*)(ws + 576 * 1024);             // 512 KB
    int* nunion   = (int*)(ws + 1088 * 1024);              // 32 B

    normalize_kernel<<<64, 256, 0, stream>>>(scores, s_norm, counts);
    topk_kernel<<<NB * NS / 4, 256, 0, stream>>>(s_norm, noise, counts);
    union_kernel<<<NB, 256, 0, stream>>>(counts, ucell, uw, nunion);
    gather_kernel<<<24 * 32, 256, 0, stream>>>(ucell, uw, nunion, x_high,
                                               (float*)d_out);
}